// Round 1
// baseline (1077.289 us; speedup 1.0000x reference)
//
#include <hip/hip_runtime.h>
#include <math.h>

// ---------------- problem constants ----------------
#define NV    50257
#define OUT_M 402056            // 8*50257
#define OUT_A 402568            // + 8*64
#define SCALE 0.125f            // 1/sqrt(64)

// ---------------- ws layout (float offsets) ----------------
#define WS_Q      0             // [8][64][64]
#define WS_HTR    32768         // [1024][8]   h transposed
#define WS_S      40960         // [64][64]    S = WG Sigma WG^T
#define WS_TV     45056         // [64]        t = 2 WG Sigma bg
#define WS_C0     45120         // [1]
#define WS_WB     45184         // [8][64]     w_b
#define WS_CONSTB 45696         // [8]
#define WS_GAMMA  45704         // [8]
#define WS_HLIE   45712         // [8][64]
#define WS_CT     46224         // [8][64]
#define WS_BROT   46736         // [8][256][64]

// =====================================================================
// K1: blocks 0..7 -> Gauss-Jordan solve (I-A)Q = (I+A) per batch, + htr
//     block 8     -> S, tvec, c0
// =====================================================================
__global__ __launch_bounds__(256) void k1_prep(
    const float* __restrict__ h_t, const float* __restrict__ A_t,
    const float* __restrict__ WG_w, const float* __restrict__ WG_b,
    const float* __restrict__ Sigma_inv, float* __restrict__ ws)
{
    const int tid = threadIdx.x;
    const int blk = blockIdx.x;
    if (blk < 8) {
        const int b = blk;
        __shared__ float W[64][128];
        for (int idx = tid; idx < 8192; idx += 256) {
            int i = idx >> 7, j = idx & 127;
            float v;
            if (j < 64) v = (i == j ? 1.0f : 0.0f) - A_t[b*4096 + i*64 + j];
            else        v = (i == (j-64) ? 1.0f : 0.0f) + A_t[b*4096 + i*64 + (j-64)];
            W[i][j] = v;
        }
        __syncthreads();
        const int i = tid & 63;
        const int g = tid >> 6;
        for (int k = 0; k < 64; ++k) {
            float f = (i == k) ? 0.0f : (W[i][k] / W[k][k]);
            __syncthreads();
            if (i != k) {
                float* wr = &W[i][g*32];
                const float* wk = &W[k][g*32];
                #pragma unroll
                for (int jj = 0; jj < 32; ++jj) wr[jj] -= f * wk[jj];
            }
            __syncthreads();
        }
        float dinv = 1.0f / W[i][i];
        #pragma unroll
        for (int jj = 0; jj < 16; ++jj) {
            int j = g*16 + jj;
            ws[WS_Q + b*4096 + i*64 + j] = W[i][64 + j] * dinv;
        }
        for (int k = tid; k < 1024; k += 256)
            ws[WS_HTR + k*8 + b] = h_t[b*1024 + k];
    } else {
        const int a = tid & 63;
        const int gu = __builtin_amdgcn_readfirstlane(tid >> 6);
        float wa[64];
        #pragma unroll
        for (int p4 = 0; p4 < 16; ++p4) {
            float4 v = *(const float4*)(WG_w + a*64 + p4*4);
            wa[p4*4+0] = v.x; wa[p4*4+1] = v.y; wa[p4*4+2] = v.z; wa[p4*4+3] = v.w;
        }
        for (int jj = 0; jj < 16; ++jj) {
            int j = gu*16 + jj;
            float acc = 0.0f;
            for (int p = 0; p < 64; ++p)
                acc += wa[p] * Sigma_inv[p] * WG_w[j*64 + p];
            ws[WS_S + a*64 + j] = acc;
        }
        if (gu == 0) {
            float t = 0.0f;
            for (int p = 0; p < 64; ++p) t += wa[p] * Sigma_inv[p] * WG_b[p];
            ws[WS_TV + a] = 2.0f * t;
            if (a == 0) {
                float c0 = 0.0f;
                for (int p = 0; p < 64; ++p) c0 += Sigma_inv[p] * WG_b[p] * WG_b[p];
                ws[WS_C0] = c0;
            }
        }
    }
}

// =====================================================================
// K3: one block per batch. q_t/h_lie GEMVs, B_rot, omega, scores,
//     softmax, c_t, c_rot, g_proj, gamma, w_b, const_b.
// =====================================================================
__global__ __launch_bounds__(256) void k3_mid(
    const float* __restrict__ h_t, const float* __restrict__ A_t,
    const float* __restrict__ B_t, const float* __restrict__ G_t,
    const float* __restrict__ WQ_w, const float* __restrict__ WQ_b,
    const float* __restrict__ WK_w, const float* __restrict__ WK_b,
    const float* __restrict__ WV_w, const float* __restrict__ WV_b,
    const float* __restrict__ WC_w, const float* __restrict__ WC_b,
    const float* __restrict__ WG_w, const float* __restrict__ WG_b,
    const float* __restrict__ wgamma_w, const float* __restrict__ wgamma_b,
    const float* __restrict__ gdown_w, const float* __restrict__ Sigma_inv,
    const float* __restrict__ hlie_w, const float* __restrict__ hlie_b,
    float* __restrict__ ws)
{
    __shared__ float Bsh[128][65];
    __shared__ float part4a[4][64];
    __shared__ float part4b[4][64];
    __shared__ float partS[4][128];
    __shared__ float scores[256];
    __shared__ float red[256];
    __shared__ float qt[64], hl[64], qk[64], cB[64], ct[64], cw[64], crot[64], gp[64], uv[64];
    __shared__ float sc[8];

    const int b = blockIdx.x;
    const int tid = threadIdx.x;
    const int lane = tid & 63;
    const int gu = __builtin_amdgcn_readfirstlane(tid >> 6);

    // ---- P0: q_t, h_lie, gamma_h part ----
    {
        float aq = 0.0f, ah = 0.0f, agam = 0.0f;
        for (int kk = 0; kk < 256; ++kk) {
            int k = gu*256 + kk;
            float hv = h_t[b*1024 + k];                 // uniform -> scalar
            aq   += hv * WQ_w[k*64 + lane];
            ah   += hv * hlie_w[k*64 + lane];
            agam += hv * wgamma_w[k];
        }
        part4a[gu][lane] = aq;
        part4b[gu][lane] = ah;
        if (lane == 0) red[gu] = agam;
    }
    __syncthreads();
    if (tid < 64) {
        qt[tid] = part4a[0][tid] + part4a[1][tid] + part4a[2][tid] + part4a[3][tid] + WQ_b[tid];
        hl[tid] = part4b[0][tid] + part4b[1][tid] + part4b[2][tid] + part4b[3][tid] + hlie_b[tid];
    }
    if (tid == 0) sc[0] = red[0] + red[1] + red[2] + red[3];   // gamma_h
    __syncthreads();

    // ---- P1: qk = WK q_t ; qkb = q_t . WK_b ----
    {
        float acc = 0.0f;
        #pragma unroll
        for (int jj = 0; jj < 16; ++jj) {
            int j = gu*16 + jj;
            acc += WK_w[lane*64 + j] * qt[j];
        }
        part4a[gu][lane] = acc;
        if (tid < 64) red[tid] = qt[tid] * WK_b[tid];
    }
    __syncthreads();
    if (tid < 64) qk[tid] = part4a[0][tid] + part4a[1][tid] + part4a[2][tid] + part4a[3][tid];
    if (tid == 0) {
        float s = 0.0f;
        for (int j = 0; j < 64; ++j) s += red[j];
        sc[1] = s;                                         // qkb
    }
    __syncthreads();

    // ---- P2: B_rot + omega + scores, in 128-row halves ----
    const float* Qb = ws + WS_Q + b*4096;
    const float* Gb = G_t + b*4096;
    for (int h = 0; h < 2; ++h) {
        for (int idx = tid; idx < 8192; idx += 256) {
            int r = idx >> 6, p = idx & 63;
            Bsh[r][p] = B_t[b*16384 + (h*128 + r)*64 + p];
        }
        __syncthreads();
        {   // rot: rows {lane, lane+64}, cols [gu*16, gu*16+16)
            float acc0[16], acc1[16];
            #pragma unroll
            for (int j = 0; j < 16; ++j) { acc0[j] = 0.0f; acc1[j] = 0.0f; }
            for (int p = 0; p < 64; ++p) {
                float b0 = Bsh[lane][p], b1 = Bsh[lane + 64][p];
                const float* qrow = Qb + p*64 + gu*16;      // uniform -> scalar
                #pragma unroll
                for (int j = 0; j < 16; ++j) {
                    float qv = qrow[j];
                    acc0[j] += b0 * qv;
                    acc1[j] += b1 * qv;
                }
            }
            __syncthreads();
            #pragma unroll
            for (int j = 0; j < 16; ++j) {
                Bsh[lane][gu*16 + j]      = acc0[j];
                Bsh[lane + 64][gu*16 + j] = acc1[j];
            }
        }
        __syncthreads();
        for (int idx = tid; idx < 8192; idx += 256) {
            int r = idx >> 6, p = idx & 63;
            ws[WS_BROT + b*16384 + (h*128 + r)*64 + p] = Bsh[r][p];
        }
        {   // omega + q.K
            float accT0[16], accT1[16];
            #pragma unroll
            for (int j = 0; j < 16; ++j) { accT0[j] = 0.0f; accT1[j] = 0.0f; }
            float s0 = 0.0f, s1 = 0.0f;
            for (int p = 0; p < 64; ++p) {
                float hlp = hl[p];
                float bb0 = Bsh[lane][p], bb1 = Bsh[lane + 64][p];
                float d0 = bb0 - hlp, d1 = bb1 - hlp;
                if (gu == 0) {
                    float qkp = qk[p];
                    s0 += bb0 * qkp;
                    s1 += bb1 * qkp;
                }
                const float* grow = Gb + p*64 + gu*16;      // uniform -> scalar
                #pragma unroll
                for (int j = 0; j < 16; ++j) {
                    float gv = grow[j];
                    accT0[j] += d0 * gv;
                    accT1[j] += d1 * gv;
                }
            }
            float of0 = 0.0f, of1 = 0.0f;
            #pragma unroll
            for (int j = 0; j < 16; ++j) {
                int col = gu*16 + j;
                float h2 = hl[col];
                of0 += accT0[j] * (Bsh[lane][col] - h2);
                of1 += accT1[j] * (Bsh[lane + 64][col] - h2);
            }
            float r0 = -0.5f * of0, r1 = -0.5f * of1;
            if (gu == 0) {
                r0 += SCALE * (s0 + sc[1]);
                r1 += SCALE * (s1 + sc[1]);
            }
            partS[gu][lane]      = r0;
            partS[gu][lane + 64] = r1;
        }
        __syncthreads();
        if (tid < 128)
            scores[h*128 + tid] = partS[0][tid] + partS[1][tid] + partS[2][tid] + partS[3][tid];
        __syncthreads();
    }

    // ---- P3: softmax over 256 ----
    float svl = scores[tid];
    red[tid] = svl;
    __syncthreads();
    for (int off = 128; off > 0; off >>= 1) {
        if (tid < off) red[tid] = fmaxf(red[tid], red[tid + off]);
        __syncthreads();
    }
    float smax = red[0];
    __syncthreads();
    float e = expf(svl - smax);
    red[tid] = e;
    __syncthreads();
    for (int off = 128; off > 0; off >>= 1) {
        if (tid < off) red[tid] += red[tid + off];
        __syncthreads();
    }
    float denom = red[0];
    __syncthreads();
    scores[tid] = e / denom;           // alpha
    __syncthreads();

    // ---- P4: cB = alpha @ B_rot ----
    {
        const float* Brb = ws + WS_BROT + b*16384;
        float acc = 0.0f;
        for (int n = gu*64; n < gu*64 + 64; ++n)
            acc += scores[n] * Brb[n*64 + lane];
        part4a[gu][lane] = acc;
    }
    __syncthreads();
    if (tid < 64) cB[tid] = part4a[0][tid] + part4a[1][tid] + part4a[2][tid] + part4a[3][tid];
    __syncthreads();

    // ---- P5: c_t = cB @ WV + bv ----
    {
        float acc = 0.0f;
        #pragma unroll
        for (int pp = 0; pp < 16; ++pp) {
            int p = gu*16 + pp;
            acc += cB[p] * WV_w[p*64 + lane];
        }
        part4a[gu][lane] = acc;
    }
    __syncthreads();
    if (tid < 64) {
        float v = part4a[0][tid] + part4a[1][tid] + part4a[2][tid] + part4a[3][tid] + WV_b[tid];
        ct[tid] = v;
        ws[WS_CT + b*64 + tid] = v;
    }
    __syncthreads();

    // ---- P6: cw = c_t @ WC + cb ----
    {
        float acc = 0.0f;
        #pragma unroll
        for (int pp = 0; pp < 16; ++pp) {
            int p = gu*16 + pp;
            acc += ct[p] * WC_w[p*64 + lane];
        }
        part4a[gu][lane] = acc;
    }
    __syncthreads();
    if (tid < 64) cw[tid] = part4a[0][tid] + part4a[1][tid] + part4a[2][tid] + part4a[3][tid] + WC_b[tid];
    __syncthreads();

    // ---- P7: c_rot = cw @ Q ----
    {
        float acc = 0.0f;
        #pragma unroll
        for (int pp = 0; pp < 16; ++pp) {
            int p = gu*16 + pp;
            acc += cw[p] * Qb[p*64 + lane];
        }
        part4a[gu][lane] = acc;
    }
    __syncthreads();
    if (tid < 64) crot[tid] = part4a[0][tid] + part4a[1][tid] + part4a[2][tid] + part4a[3][tid];
    __syncthreads();

    // ---- P8: g_proj = g_t @ gdown ; gamma g & c parts ----
    {
        float accp = 0.0f, accg = 0.0f;
        const int s0i = gu * 504;
        const int s1i = s0i + 504;
        int i = 0;
        while (63*(i+1) - ((i+1)*i)/2 <= s0i) ++i;
        int j = i + 1 + (s0i - (63*i - (i*(i-1))/2));
        for (int sidx = s0i; sidx < s1i; ++sidx) {
            float av = A_t[b*4096 + i*64 + j];             // uniform -> scalar
            accp += av * gdown_w[sidx*64 + lane];
            accg += av * wgamma_w[1088 + sidx];
            if (++j == 64) { ++i; j = i + 1; }
        }
        part4a[gu][lane] = accp;
        if (lane == 0) red[gu] = accg;
        if (tid < 64) red[64 + tid] = ct[tid] * wgamma_w[1024 + tid];
    }
    __syncthreads();
    if (tid < 64) {
        float gpv = part4a[0][tid] + part4a[1][tid] + part4a[2][tid] + part4a[3][tid];
        gp[tid] = gpv;
        uv[tid] = 2.0f * Sigma_inv[tid] * gpv;
    }
    if (tid == 0) {
        float gc = 0.0f;
        for (int j2 = 0; j2 < 64; ++j2) gc += red[64 + j2];
        float z = sc[0] + gc + (red[0] + red[1] + red[2] + red[3]) + wgamma_b[0];
        ws[WS_GAMMA + b] = 1.0f / (1.0f + expf(-z));
    }
    __syncthreads();

    // ---- P9: w_b = scale*crot + WG @ u ; const_b = bg.u - sum gp^2 sigma ----
    {
        float acc = 0.0f;
        #pragma unroll
        for (int pp = 0; pp < 16; ++pp) {
            int p = gu*16 + pp;
            acc += WG_w[lane*64 + p] * uv[p];
        }
        part4a[gu][lane] = acc;
        if (tid < 64) red[tid] = WG_b[tid]*uv[tid] - gp[tid]*gp[tid]*Sigma_inv[tid];
    }
    __syncthreads();
    if (tid < 64) {
        ws[WS_WB + b*64 + tid] = SCALE * crot[tid]
            + part4a[0][tid] + part4a[1][tid] + part4a[2][tid] + part4a[3][tid];
        ws[WS_HLIE + b*64 + tid] = hl[tid];
    }
    if (tid == 0) {
        float cbv = 0.0f;
        for (int j2 = 0; j2 < 64; ++j2) cbv += red[j2];
        ws[WS_CONSTB + b] = cbv;
    }
}

// =====================================================================
// K4: fused logits. 1 v per thread; sv quadratic in-block; base GEMV
//     streams WO coalesced; h via uniform scalar loads from ws.
// =====================================================================
__global__ __launch_bounds__(128) void k4_logits(
    const float* __restrict__ E, const float* __restrict__ WO_w,
    const float* __restrict__ ws, float* __restrict__ out)
{
    __shared__ float Esh[128][65];
    __shared__ float partQ[2][128];
    __shared__ float svsh[128];

    const int tid = threadIdx.x;
    const int vb = blockIdx.x * 128;
    const int lane = tid & 63;
    const int gu = __builtin_amdgcn_readfirstlane(tid >> 6);

    for (int idx = tid; idx < 8192; idx += 128) {
        int r = idx >> 6, p = idx & 63;
        int v = vb + r;
        Esh[r][p] = (v < NV) ? E[v*64 + p] : 0.0f;
    }
    __syncthreads();

    {   // sv = e^T S e + t.e + c0
        const float* S  = ws + WS_S;
        const float* TV = ws + WS_TV;
        float a0[32], a1[32];
        #pragma unroll
        for (int j = 0; j < 32; ++j) { a0[j] = 0.0f; a1[j] = 0.0f; }
        for (int p = 0; p < 64; ++p) {
            float e0 = Esh[lane][p], e1 = Esh[lane + 64][p];
            const float* srow = S + p*64 + gu*32;           // uniform -> scalar
            #pragma unroll
            for (int j = 0; j < 32; ++j) {
                float s = srow[j];
                a0[j] += e0 * s;
                a1[j] += e1 * s;
            }
        }
        float q0 = 0.0f, q1 = 0.0f;
        #pragma unroll
        for (int j = 0; j < 32; ++j) {
            int col = gu*32 + j;
            float tv = TV[col];
            q0 += (a0[j] + tv) * Esh[lane][col];
            q1 += (a1[j] + tv) * Esh[lane + 64][col];
        }
        partQ[gu][lane]      = q0;
        partQ[gu][lane + 64] = q1;
    }
    __syncthreads();
    svsh[tid] = partQ[0][tid] + partQ[1][tid] + ws[WS_C0];
    __syncthreads();

    const int v = vb + tid;
    const bool vok = v < NV;
    const int vv = vok ? v : (NV - 1);

    float gd[8];
    #pragma unroll
    for (int bb = 0; bb < 8; ++bb) gd[bb] = 0.0f;
    {
        const float4* E4 = (const float4*)E;
        const float* WB = ws + WS_WB;
        #pragma unroll 4
        for (int p4 = 0; p4 < 16; ++p4) {
            float4 e4 = E4[vv*16 + p4];
            #pragma unroll
            for (int bb = 0; bb < 8; ++bb) {
                float4 w4 = *(const float4*)(WB + bb*64 + p4*4);   // uniform
                gd[bb] += e4.x*w4.x + e4.y*w4.y + e4.z*w4.z + e4.w*w4.w;
            }
        }
    }

    float acc[8];
    #pragma unroll
    for (int bb = 0; bb < 8; ++bb) acc[bb] = 0.0f;
    {
        const float* HTR = ws + WS_HTR;
        const float* wo = WO_w + vv;
        for (int k = 0; k < 1024; k += 8) {
            float w[8];
            #pragma unroll
            for (int u = 0; u < 8; ++u) w[u] = wo[(long)(k + u) * NV];
            #pragma unroll
            for (int u = 0; u < 8; ++u) {
                const float* hp = HTR + (k + u)*8;                 // uniform
                #pragma unroll
                for (int bb = 0; bb < 8; ++bb)
                    acc[bb] = fmaf(hp[bb], w[u], acc[bb]);
            }
        }
    }

    if (vok) {
        const float* GM = ws + WS_GAMMA;
        const float* CB = ws + WS_CONSTB;
        float svv = svsh[tid];
        #pragma unroll
        for (int bb = 0; bb < 8; ++bb) {
            float gl = gd[bb] + CB[bb] - svv;
            out[bb*NV + v] = fmaf(GM[bb], gl, acc[bb]);
        }
    }
}

// =====================================================================
// K5: per-batch: top-8, H, E_exp, rho, mu, m_next, A_next
// =====================================================================
__global__ __launch_bounds__(256) void k5_final(
    const float* __restrict__ h_t, const float* __restrict__ A_t,
    const float* __restrict__ E, const float* __restrict__ e_mask,
    const float* __restrict__ G_t,
    const float* __restrict__ wmu_w, const float* __restrict__ wmu_b,
    const float* __restrict__ ws, float* __restrict__ out)
{
    __shared__ float candv[2048];
    __shared__ int   candi[2048];
    __shared__ float redv[256];
    __shared__ int   redi[256];
    __shared__ int   redo[256];
    __shared__ float sred[256];
    __shared__ float t8v[8];
    __shared__ int   t8i[8];
    __shared__ float toppsh[8];
    __shared__ float uvec[64], eexp[64], msh[64], emsh[64];
    __shared__ float scal[4];
    __shared__ int   iscal[1];

    const int b = blockIdx.x;
    const int tid = threadIdx.x;
    const float* lg = out + b*NV;

    // ---- local top-8 ----
    float lv[8]; int li[8];
    #pragma unroll
    for (int u = 0; u < 8; ++u) { lv[u] = -INFINITY; li[u] = 0x7fffffff; }
    for (int v = tid; v < NV; v += 256) {
        float x = lg[v];
        if (x > lv[7]) {
            int p = 7;
            while (p > 0 && x > lv[p-1]) { lv[p] = lv[p-1]; li[p] = li[p-1]; --p; }
            lv[p] = x; li[p] = v;
        }
    }
    #pragma unroll
    for (int u = 0; u < 8; ++u) { candv[tid*8 + u] = lv[u]; candi[tid*8 + u] = li[u]; }
    __syncthreads();

    // ---- 8 extractions of global max ----
    int ptr = 0;
    for (int it = 0; it < 8; ++it) {
        redv[tid] = (ptr < 8) ? candv[tid*8 + ptr] : -INFINITY;
        redi[tid] = (ptr < 8) ? candi[tid*8 + ptr] : 0x7fffffff;
        redo[tid] = tid;
        __syncthreads();
        for (int off = 128; off > 0; off >>= 1) {
            if (tid < off) {
                float ov = redv[tid + off]; int oi = redi[tid + off];
                if (ov > redv[tid] || (ov == redv[tid] && oi < redi[tid])) {
                    redv[tid] = ov; redi[tid] = oi; redo[tid] = redo[tid + off];
                }
            }
            __syncthreads();
        }
        if (tid == 0) { t8v[it] = redv[0]; t8i[it] = redi[0]; iscal[0] = redo[0]; }
        __syncthreads();
        if (tid == iscal[0]) ++ptr;
        __syncthreads();
    }

    // ---- softmax stats / entropy ----
    float M = t8v[0];
    float s1 = 0.0f, s2 = 0.0f;
    for (int v = tid; v < NV; v += 256) {
        float x = lg[v];
        float ee = expf(x - M);
        s1 += ee; s2 += x * ee;
    }
    redv[tid] = s1; sred[tid] = s2;
    __syncthreads();
    for (int off = 128; off > 0; off >>= 1) {
        if (tid < off) { redv[tid] += redv[tid + off]; sred[tid] += sred[tid + off]; }
        __syncthreads();
    }
    if (tid == 0) {
        float S1 = redv[0], S2 = sred[0];
        scal[0] = M + logf(S1) - S2 / S1;       // H
        float ts = 0.0f, tvv[8];
        #pragma unroll
        for (int u = 0; u < 8; ++u) { tvv[u] = expf(t8v[u] - M); ts += tvv[u]; }
        #pragma unroll
        for (int u = 0; u < 8; ++u) toppsh[u] = tvv[u] / ts;
    }
    __syncthreads();

    // ---- E_exp = (topp @ E_g) @ Q ----
    if (tid < 64) {
        float u_ = 0.0f;
        #pragma unroll
        for (int j = 0; j < 8; ++j) u_ += toppsh[j] * E[t8i[j]*64 + tid];
        uvec[tid] = u_;
    }
    __syncthreads();
    if (tid < 64) {
        const float* Qb = ws + WS_Q + b*4096;
        float a = 0.0f;
        for (int p = 0; p < 64; ++p) a += uvec[p] * Qb[p*64 + tid];
        eexp[tid] = a;
    }
    __syncthreads();

    // ---- rho = (E_exp - h_lie) G (E_exp - h_lie) ----
    {
        const float* Gb = G_t + b*4096;
        const float* HL = ws + WS_HLIE + b*64;
        float a = 0.0f;
        #pragma unroll 4
        for (int t2 = 0; t2 < 16; ++t2) {
            int idx = tid*16 + t2;
            int p = idx >> 6, q = idx & 63;
            a += (eexp[p] - HL[p]) * Gb[idx] * (eexp[q] - HL[q]);
        }
        redv[tid] = a;
    }
    __syncthreads();
    for (int off = 128; off > 0; off >>= 1) {
        if (tid < off) redv[tid] += redv[tid + off];
        __syncthreads();
    }
    if (tid == 0) scal[1] = redv[0];            // rho
    __syncthreads();

    // ---- mu ----
    float pm = 0.0f;
    for (int k = tid; k < 1024; k += 256) pm += h_t[b*1024 + k] * wmu_w[k];
    if (tid < 64) pm += ws[WS_CT + b*64 + tid] * wmu_w[1024 + tid];
    redv[tid] = pm;
    __syncthreads();
    for (int off = 128; off > 0; off >>= 1) {
        if (tid < off) redv[tid] += redv[tid + off];
        __syncthreads();
    }
    if (tid == 0) {
        float z = redv[0] + scal[0]*wmu_w[1088] + scal[1]*wmu_w[1089] + wmu_b[0];
        scal[2] = 1.0f / (1.0f + expf(-z));     // mu
    }
    __syncthreads();

    // ---- m_next, A_next ----
    if (tid < 64) {
        float mu = scal[2];
        float em = e_mask[b*64 + tid];
        float m = mu*em + (1.0f - mu)*eexp[tid];
        out[OUT_M + b*64 + tid] = m;
        msh[tid] = m;
        emsh[tid] = em;
    }
    __syncthreads();
    for (int idx = tid; idx < 4096; idx += 256) {
        int i = idx >> 6, j = idx & 63;
        out[OUT_A + b*4096 + idx] = A_t[b*4096 + idx]
            + 0.1f*(msh[i]*emsh[j] - msh[j]*emsh[i]);
    }
}

// =====================================================================
extern "C" void kernel_launch(void* const* d_in, const int* in_sizes, int n_in,
                              void* d_out, int out_size, void* d_ws, size_t ws_size,
                              hipStream_t stream)
{
    const float* h_t      = (const float*)d_in[0];
    const float* A_t      = (const float*)d_in[1];
    const float* B_t      = (const float*)d_in[2];
    const float* E        = (const float*)d_in[3];
    const float* e_mask   = (const float*)d_in[4];
    const float* G_t      = (const float*)d_in[5];
    // d_in[6] = z0 (unused by reference)
    const float* WQ_w     = (const float*)d_in[7];
    const float* WQ_b     = (const float*)d_in[8];
    const float* WK_w     = (const float*)d_in[9];
    const float* WK_b     = (const float*)d_in[10];
    const float* WV_w     = (const float*)d_in[11];
    const float* WV_b     = (const float*)d_in[12];
    const float* WC_w     = (const float*)d_in[13];
    const float* WC_b     = (const float*)d_in[14];
    const float* WO_w     = (const float*)d_in[15];
    const float* WG_w     = (const float*)d_in[16];
    const float* WG_b     = (const float*)d_in[17];
    const float* wgamma_w = (const float*)d_in[18];
    const float* wgamma_b = (const float*)d_in[19];
    const float* wmu_w    = (const float*)d_in[20];
    const float* wmu_b    = (const float*)d_in[21];
    const float* gdown_w  = (const float*)d_in[22];
    const float* Sigma_inv= (const float*)d_in[23];
    const float* hlie_w   = (const float*)d_in[24];
    const float* hlie_b   = (const float*)d_in[25];
    float* out = (float*)d_out;
    float* ws  = (float*)d_ws;

    k1_prep<<<9, 256, 0, stream>>>(h_t, A_t, WG_w, WG_b, Sigma_inv, ws);
    k3_mid<<<8, 256, 0, stream>>>(h_t, A_t, B_t, G_t, WQ_w, WQ_b, WK_w, WK_b,
                                  WV_w, WV_b, WC_w, WC_b, WG_w, WG_b,
                                  wgamma_w, wgamma_b, gdown_w, Sigma_inv,
                                  hlie_w, hlie_b, ws);
    k4_logits<<<393, 128, 0, stream>>>(E, WO_w, ws, out);
    k5_final<<<8, 256, 0, stream>>>(h_t, A_t, E, e_mask, G_t, wmu_w, wmu_b, ws, out);
}

// Round 2
// 747.512 us; speedup vs baseline: 1.4412x; 1.4412x over previous
//
#include <hip/hip_runtime.h>
#include <math.h>

// ---------------- problem constants ----------------
#define NV    50257
#define OUT_M 402056            // 8*50257
#define OUT_A 402568            // + 8*64
#define SCALE 0.125f            // 1/sqrt(64)

// ---------------- ws layout (float offsets) ----------------
#define WS_Q      0             // [8][64][64]
#define WS_HTR    32768         // [1024][8]
#define WS_S      40960         // [64][64]  S = WG Sigma WG^T
#define WS_TV     45056         // [64]
#define WS_C0     45120         // [1] (pad 8)
#define WS_IU     45128         // [2016] int: packed i*64+j upper-tri pairs
#define WS_HLIE   47144         // [8][64]
#define WS_W1     47656         // [8][64]
#define WS_S0     48168         // [8]
#define WS_GH     48176         // [8]
#define WS_WMAT   48192         // [8][64][64]  W = Q G Q^T
#define WS_SC     80960         // [8][256] scores
#define WS_WB     83008         // [8][64]
#define WS_CONSTB 83520         // [8]
#define WS_GAMMA  83528         // [8]
#define WS_CT     83536         // [8][64]
#define WS_P6     84048         // [8][4][20] top-k partials

// =====================================================================
// K1: blocks 0..7 -> Gauss-Jordan solve (I-A)Q = (I+A) per batch + htr
//     block 8     -> S, tvec, c0, iu pair table
// =====================================================================
__global__ __launch_bounds__(256) void k1_prep(
    const float* __restrict__ h_t, const float* __restrict__ A_t,
    const float* __restrict__ WG_w, const float* __restrict__ WG_b,
    const float* __restrict__ Sigma_inv, float* __restrict__ ws)
{
    const int tid = threadIdx.x;
    const int blk = blockIdx.x;
    if (blk < 8) {
        const int b = blk;
        __shared__ float W[64][128];
        for (int idx = tid; idx < 8192; idx += 256) {
            int i = idx >> 7, j = idx & 127;
            float v;
            if (j < 64) v = (i == j ? 1.0f : 0.0f) - A_t[b*4096 + i*64 + j];
            else        v = (i == (j-64) ? 1.0f : 0.0f) + A_t[b*4096 + i*64 + (j-64)];
            W[i][j] = v;
        }
        __syncthreads();
        const int i = tid & 63;
        const int g = tid >> 6;
        for (int k = 0; k < 64; ++k) {
            float f = (i == k) ? 0.0f : (W[i][k] / W[k][k]);
            __syncthreads();
            if (i != k) {
                float* wr = &W[i][g*32];
                const float* wk = &W[k][g*32];
                #pragma unroll
                for (int jj = 0; jj < 32; ++jj) wr[jj] -= f * wk[jj];
            }
            __syncthreads();
        }
        float dinv = 1.0f / W[i][i];
        #pragma unroll
        for (int jj = 0; jj < 16; ++jj) {
            int j = g*16 + jj;
            ws[WS_Q + b*4096 + i*64 + j] = W[i][64 + j] * dinv;
        }
        for (int k = tid; k < 1024; k += 256)
            ws[WS_HTR + k*8 + b] = h_t[b*1024 + k];
    } else {
        const int a = tid & 63;
        const int gu = __builtin_amdgcn_readfirstlane(tid >> 6);
        float wa[64];
        #pragma unroll
        for (int p4 = 0; p4 < 16; ++p4) {
            float4 v = *(const float4*)(WG_w + a*64 + p4*4);
            wa[p4*4+0] = v.x; wa[p4*4+1] = v.y; wa[p4*4+2] = v.z; wa[p4*4+3] = v.w;
        }
        for (int jj = 0; jj < 16; ++jj) {
            int j = gu*16 + jj;
            float acc = 0.0f;
            for (int p = 0; p < 64; ++p)
                acc += wa[p] * Sigma_inv[p] * WG_w[j*64 + p];
            ws[WS_S + a*64 + j] = acc;
        }
        if (gu == 0) {
            float t = 0.0f;
            for (int p = 0; p < 64; ++p) t += wa[p] * Sigma_inv[p] * WG_b[p];
            ws[WS_TV + a] = 2.0f * t;
            if (a == 0) {
                float c0 = 0.0f;
                for (int p = 0; p < 64; ++p) c0 += Sigma_inv[p] * WG_b[p] * WG_b[p];
                ws[WS_C0] = c0;
            }
        }
        // upper-tri pair table
        for (int s = tid; s < 2016; s += 256) {
            int i = 0, f = 0;
            while (f + (63 - i) <= s) { f += 63 - i; ++i; }
            int j = i + 1 + (s - f);
            ((int*)ws)[WS_IU + s] = i*64 + j;
        }
    }
}

// =====================================================================
// K2: one block per batch. q_t/h_lie GEMVs, qkvec, Ghl, w1, s0, gh,
//     W = Q G Q^T. All matrices staged in LDS.
// =====================================================================
__global__ __launch_bounds__(256) void k2_batch(
    const float* __restrict__ h_t, const float* __restrict__ G_t,
    const float* __restrict__ WQ_w, const float* __restrict__ WQ_b,
    const float* __restrict__ WK_w, const float* __restrict__ WK_b,
    const float* __restrict__ wgamma_w,
    const float* __restrict__ hlie_w, const float* __restrict__ hlie_b,
    float* __restrict__ ws)
{
    __shared__ float Qsh[64][65], Qtsh[64][65], Gsh[64][65];
    __shared__ float part[4][64], partb[4][64];
    __shared__ float qt[64], hl[64], qkv[64], ghl[64], v0[64], red64[64];
    __shared__ float scal[4];

    const int b = blockIdx.x, tid = threadIdx.x;
    const int lane = tid & 63;
    const int gu = __builtin_amdgcn_readfirstlane(tid >> 6);
    const int col0 = gu * 16;
    const float* Qb = ws + WS_Q + b*4096;
    const float* Gb = G_t + b*4096;

    for (int idx = tid; idx < 4096; idx += 256) {
        int r = idx >> 6, c = idx & 63;
        float q = Qb[idx];
        Qsh[r][c] = q; Qtsh[c][r] = q;
        Gsh[r][c] = Gb[idx];
    }
    // GEMVs from h (loads pipelined; addresses wave-uniform for h)
    {
        float aq = 0, ah = 0, ag = 0;
        for (int kk = 0; kk < 256; ++kk) {
            int k = gu*256 + kk;
            float hv = h_t[b*1024 + k];
            aq += hv * WQ_w[k*64 + lane];
            ah += hv * hlie_w[k*64 + lane];
            ag += hv * wgamma_w[k];
        }
        part[gu][lane] = aq; partb[gu][lane] = ah;
        if (lane == 0) red64[gu] = ag;
    }
    __syncthreads();
    if (tid < 64) {
        qt[tid] = part[0][tid]+part[1][tid]+part[2][tid]+part[3][tid] + WQ_b[tid];
        hl[tid] = partb[0][tid]+partb[1][tid]+partb[2][tid]+partb[3][tid] + hlie_b[tid];
    }
    if (tid == 0) scal[0] = red64[0]+red64[1]+red64[2]+red64[3];   // gamma_h
    __syncthreads();
    // qkvec = WK q_t ; qkb = q_t . WK_b
    {
        float acc = 0;
        #pragma unroll
        for (int jj = 0; jj < 16; ++jj) acc += WK_w[lane*64 + col0 + jj] * qt[col0 + jj];
        part[gu][lane] = acc;
    }
    if (tid < 64) red64[tid] = qt[tid] * WK_b[tid];
    __syncthreads();
    if (tid < 64) qkv[tid] = part[0][tid]+part[1][tid]+part[2][tid]+part[3][tid];
    if (tid == 0) { float s = 0; for (int j = 0; j < 64; ++j) s += red64[j]; scal[1] = s; }
    __syncthreads();
    // ghl = G hl ; hGh
    {
        float acc = 0;
        #pragma unroll
        for (int jj = 0; jj < 16; ++jj) acc += Gsh[lane][col0 + jj] * hl[col0 + jj];
        part[gu][lane] = acc;
    }
    __syncthreads();
    if (tid < 64) {
        float g = part[0][tid]+part[1][tid]+part[2][tid]+part[3][tid];
        ghl[tid] = g; red64[tid] = hl[tid]*g;
    }
    __syncthreads();
    if (tid == 0) { float s = 0; for (int j = 0; j < 64; ++j) s += red64[j]; scal[2] = s; }
    if (tid < 64) v0[tid] = SCALE*qkv[tid] + ghl[tid];
    __syncthreads();
    // w1 = Q v0
    {
        float acc = 0;
        #pragma unroll
        for (int jj = 0; jj < 16; ++jj) acc += Qsh[lane][col0+jj] * v0[col0+jj];
        part[gu][lane] = acc;
    }
    __syncthreads();
    if (tid < 64) {
        ws[WS_W1 + b*64 + tid] = part[0][tid]+part[1][tid]+part[2][tid]+part[3][tid];
        ws[WS_HLIE + b*64 + tid] = hl[tid];
    }
    if (tid == 0) {
        ws[WS_S0 + b] = SCALE*scal[1] - 0.5f*scal[2];
        ws[WS_GH + b] = scal[0];
    }
    // T = Q G into regs
    float t[16];
    #pragma unroll
    for (int j = 0; j < 16; ++j) t[j] = 0;
    for (int r = 0; r < 64; ++r) {
        float qv = Qsh[lane][r];
        #pragma unroll
        for (int j = 0; j < 16; ++j) t[j] += qv * Gsh[r][col0+j];
    }
    __syncthreads();
    #pragma unroll
    for (int j = 0; j < 16; ++j) Gsh[lane][col0+j] = t[j];   // Gsh now holds T
    __syncthreads();
    // W = T Q^T ; W symmetric -> store at transposed slot for coalescing
    float w[16];
    #pragma unroll
    for (int j = 0; j < 16; ++j) w[j] = 0;
    for (int q = 0; q < 64; ++q) {
        float tv = Gsh[lane][q];
        #pragma unroll
        for (int j = 0; j < 16; ++j) w[j] += tv * Qtsh[q][col0+j];
    }
    #pragma unroll
    for (int j = 0; j < 16; ++j)
        ws[WS_WMAT + b*4096 + (col0+j)*64 + lane] = w[j];
}

// =====================================================================
// K3: 32 blocks = (b, quarter). scores via b W b^T from LDS.
// =====================================================================
__global__ __launch_bounds__(256) void k3_scores(
    const float* __restrict__ B_t, float* __restrict__ ws)
{
    __shared__ float Bsh[64][65];
    __shared__ float Wsh[64][64];
    __shared__ float w1sh[64];
    __shared__ float part[4][64];
    const int b = blockIdx.x >> 2, q4 = blockIdx.x & 3;
    const int tid = threadIdx.x, lane = tid & 63;
    const int gu = __builtin_amdgcn_readfirstlane(tid >> 6);
    const int col0 = gu * 16;
    for (int idx = tid; idx < 4096; idx += 256) {
        int r = idx >> 6, c = idx & 63;
        Bsh[r][c] = B_t[b*16384 + (q4*64 + r)*64 + c];
        Wsh[r][c] = ws[WS_WMAT + b*4096 + idx];
    }
    if (tid < 64) w1sh[tid] = ws[WS_W1 + b*64 + tid];
    __syncthreads();
    float t[16];
    #pragma unroll
    for (int j = 0; j < 16; ++j) t[j] = 0;
    for (int p = 0; p < 64; ++p) {
        float bv = Bsh[lane][p];
        #pragma unroll
        for (int j = 0; j < 16; ++j) t[j] += bv * Wsh[p][col0+j];
    }
    float ps = 0;
    #pragma unroll
    for (int j = 0; j < 16; ++j) ps += (w1sh[col0+j] - 0.5f*t[j]) * Bsh[lane][col0+j];
    part[gu][lane] = ps;
    __syncthreads();
    if (tid < 64)
        ws[WS_SC + b*256 + q4*64 + tid] =
            part[0][tid]+part[1][tid]+part[2][tid]+part[3][tid] + ws[WS_S0 + b];
}

// =====================================================================
// K4: per batch: softmax(alpha), c chain, g_proj (table), gamma, w_b.
// =====================================================================
__global__ __launch_bounds__(256) void k4_mid(
    const float* __restrict__ A_t, const float* __restrict__ B_t,
    const float* __restrict__ WV_w, const float* __restrict__ WV_b,
    const float* __restrict__ WC_w, const float* __restrict__ WC_b,
    const float* __restrict__ WG_w, const float* __restrict__ WG_b,
    const float* __restrict__ wgamma_w, const float* __restrict__ wgamma_b,
    const float* __restrict__ gdown_w, const float* __restrict__ Sigma_inv,
    float* __restrict__ ws)
{
    __shared__ float alpha[256], rr[256];
    __shared__ float part[4][64];
    __shared__ float cBr[64], cB[64], ct[64], cw[64], crot[64], gp[64], uv[64];
    const int b = blockIdx.x, tid = threadIdx.x, lane = tid & 63;
    const int gu = __builtin_amdgcn_readfirstlane(tid >> 6);
    const int col0 = gu * 16;
    const float* Qb = ws + WS_Q + b*4096;

    float sv = ws[WS_SC + b*256 + tid];
    rr[tid] = sv; __syncthreads();
    for (int off = 128; off > 0; off >>= 1) { if (tid < off) rr[tid] = fmaxf(rr[tid], rr[tid+off]); __syncthreads(); }
    float smax = rr[0]; __syncthreads();
    float e = expf(sv - smax);
    rr[tid] = e; __syncthreads();
    for (int off = 128; off > 0; off >>= 1) { if (tid < off) rr[tid] += rr[tid+off]; __syncthreads(); }
    float den = rr[0]; __syncthreads();
    alpha[tid] = e / den;
    __syncthreads();
    // cB_raw = alpha @ B
    {
        float acc = 0;
        for (int nn = 0; nn < 64; ++nn) {
            int n = gu*64 + nn;
            acc += alpha[n] * B_t[b*16384 + n*64 + lane];
        }
        part[gu][lane] = acc;
    }
    __syncthreads();
    if (tid < 64) cBr[tid] = part[0][tid]+part[1][tid]+part[2][tid]+part[3][tid];
    __syncthreads();
    // cB = cBr @ Q
    {
        float acc = 0;
        #pragma unroll
        for (int pp = 0; pp < 16; ++pp) { int p = col0+pp; acc += cBr[p]*Qb[p*64+lane]; }
        part[gu][lane] = acc;
    }
    __syncthreads();
    if (tid < 64) cB[tid] = part[0][tid]+part[1][tid]+part[2][tid]+part[3][tid];
    __syncthreads();
    // c_t = cB @ WV + bv
    {
        float acc = 0;
        #pragma unroll
        for (int pp = 0; pp < 16; ++pp) { int p = col0+pp; acc += cB[p]*WV_w[p*64+lane]; }
        part[gu][lane] = acc;
    }
    __syncthreads();
    if (tid < 64) {
        float v = part[0][tid]+part[1][tid]+part[2][tid]+part[3][tid] + WV_b[tid];
        ct[tid] = v; ws[WS_CT + b*64 + tid] = v;
    }
    __syncthreads();
    // cw = c_t @ WC + cb
    {
        float acc = 0;
        #pragma unroll
        for (int pp = 0; pp < 16; ++pp) { int p = col0+pp; acc += ct[p]*WC_w[p*64+lane]; }
        part[gu][lane] = acc;
    }
    __syncthreads();
    if (tid < 64) cw[tid] = part[0][tid]+part[1][tid]+part[2][tid]+part[3][tid] + WC_b[tid];
    __syncthreads();
    // crot = cw @ Q
    {
        float acc = 0;
        #pragma unroll
        for (int pp = 0; pp < 16; ++pp) { int p = col0+pp; acc += cw[p]*Qb[p*64+lane]; }
        part[gu][lane] = acc;
    }
    __syncthreads();
    if (tid < 64) crot[tid] = part[0][tid]+part[1][tid]+part[2][tid]+part[3][tid];
    __syncthreads();
    // g_proj = g_t @ gdown (pair table), gamma parts
    {
        const int* iu = (const int*)ws + WS_IU;
        float accp = 0, accg = 0;
        #pragma unroll 4
        for (int ss = 0; ss < 504; ++ss) {
            int s = gu*504 + ss;
            int ij = iu[s];
            float av = A_t[b*4096 + ij];
            accp += av * gdown_w[s*64 + lane];
            accg += av * wgamma_w[1088 + s];
        }
        part[gu][lane] = accp;
        if (lane == 0) rr[gu] = accg;
    }
    if (tid < 64) rr[64 + tid] = ct[tid] * wgamma_w[1024 + tid];
    __syncthreads();
    if (tid < 64) {
        float g = part[0][tid]+part[1][tid]+part[2][tid]+part[3][tid];
        gp[tid] = g; uv[tid] = 2.0f * Sigma_inv[tid] * g;
    }
    if (tid == 0) {
        float gc = 0; for (int j = 0; j < 64; ++j) gc += rr[64 + j];
        float z = ws[WS_GH + b] + gc + rr[0]+rr[1]+rr[2]+rr[3] + wgamma_b[0];
        ws[WS_GAMMA + b] = 1.0f / (1.0f + expf(-z));
    }
    __syncthreads();
    // w_b = scale*crot + WG u ; const_b = bg.u - sum gp^2 sig
    {
        float acc = 0;
        #pragma unroll
        for (int pp = 0; pp < 16; ++pp) { int p = col0+pp; acc += WG_w[lane*64+p]*uv[p]; }
        part[gu][lane] = acc;
    }
    if (tid < 64) rr[tid] = WG_b[tid]*uv[tid] - gp[tid]*gp[tid]*Sigma_inv[tid];
    __syncthreads();
    if (tid < 64)
        ws[WS_WB + b*64 + tid] = SCALE*crot[tid]
            + part[0][tid]+part[1][tid]+part[2][tid]+part[3][tid];
    if (tid == 0) { float s = 0; for (int j = 0; j < 64; ++j) s += rr[j]; ws[WS_CONSTB + b] = s; }
}

// =====================================================================
// K5: fused logits. Phase1: sv quadratic (E,S staged in LDS).
//     Phase2: gd + WO stream with h broadcast from LDS.
// =====================================================================
#define KU 16
__global__ __launch_bounds__(128) void k5_logits(
    const float* __restrict__ E, const float* __restrict__ WO_w,
    const float* __restrict__ ws, float* __restrict__ out)
{
    __shared__ float smem[12608];   // 50.4 KB, two-phase reuse
    const int tid = threadIdx.x;
    const int vb = blockIdx.x * 128;
    const int v = vb + tid;
    const bool vok = v < NV;
    const int vv = vok ? v : NV - 1;

    // phase 1 partition
    float* Esh  = smem;            // [128][66]
    float* Ssh  = smem + 8448;     // [64][64]
    float* tvsh = smem + 12544;    // [64]
    for (int idx = tid; idx < 8192; idx += 128) {
        int r = idx >> 6, c = idx & 63;
        int vr = vb + r; if (vr >= NV) vr = NV - 1;
        Esh[r*66 + c] = E[vr*64 + c];
    }
    for (int idx = tid; idx < 4096; idx += 128) Ssh[idx] = ws[WS_S + idx];
    if (tid < 64) tvsh[tid] = ws[WS_TV + tid];
    __syncthreads();
    float sv = ws[WS_C0];
    {
        const float* er = Esh + tid*66;
        for (int jb = 0; jb < 4; ++jb) {
            float t[16];
            #pragma unroll
            for (int j = 0; j < 16; ++j) t[j] = 0;
            for (int p = 0; p < 64; ++p) {
                float ep = er[p];
                #pragma unroll
                for (int j = 0; j < 16; ++j) t[j] += ep * Ssh[p*64 + jb*16 + j];
            }
            #pragma unroll
            for (int j = 0; j < 16; ++j) sv += (t[j] + tvsh[jb*16+j]) * er[jb*16+j];
        }
    }
    __syncthreads();
    // phase 2 partition
    float* hsh  = smem;            // [1024][8]
    float* wbsh = smem + 8192;     // [8][64]
    float* gmsh = smem + 8704;     // [8]
    float* cbsh = smem + 8712;     // [8]
    for (int idx = tid; idx < 8192; idx += 128) hsh[idx] = ws[WS_HTR + idx];
    for (int idx = tid; idx < 512; idx += 128) wbsh[idx] = ws[WS_WB + idx];
    if (tid < 8) { gmsh[tid] = ws[WS_GAMMA + tid]; cbsh[tid] = ws[WS_CONSTB + tid]; }
    __syncthreads();
    // gd[b] = e . w_b
    float gd[8];
    #pragma unroll
    for (int bb = 0; bb < 8; ++bb) gd[bb] = 0;
    {
        const float4* E4 = (const float4*)(E + (size_t)vv * 64);
        #pragma unroll 4
        for (int p4 = 0; p4 < 16; ++p4) {
            float4 e4 = E4[p4];
            #pragma unroll
            for (int bb = 0; bb < 8; ++bb) {
                const float* wp = wbsh + bb*64 + p4*4;
                gd[bb] += e4.x*wp[0] + e4.y*wp[1] + e4.z*wp[2] + e4.w*wp[3];
            }
        }
    }
    // base logits: stream WO column, h from LDS broadcast
    float acc[8];
    #pragma unroll
    for (int bb = 0; bb < 8; ++bb) acc[bb] = 0;
    {
        const float* wo = WO_w + vv;
        for (int k0 = 0; k0 < 1024; k0 += KU) {
            float wr[KU];
            #pragma unroll
            for (int u = 0; u < KU; ++u) wr[u] = wo[(size_t)(k0 + u) * NV];
            #pragma unroll
            for (int u = 0; u < KU; ++u) {
                const float* hp = hsh + (k0 + u)*8;
                #pragma unroll
                for (int bb = 0; bb < 8; ++bb) acc[bb] = fmaf(hp[bb], wr[u], acc[bb]);
            }
        }
    }
    if (vok) {
        #pragma unroll
        for (int bb = 0; bb < 8; ++bb) {
            float gl = gd[bb] + cbsh[bb] - sv;
            out[bb*NV + v] = fmaf(gmsh[bb], gl, acc[bb]);
        }
    }
}

// =====================================================================
// K6a: 32 blocks = (b, quarter): partial top-8 + rescalable softmax sums
// =====================================================================
#define NQ 12565
__global__ __launch_bounds__(256) void k6a_scan(
    const float* __restrict__ outl, float* __restrict__ ws)
{
    __shared__ float candv[2048];
    __shared__ int   candi[2048];
    __shared__ float redv[256];
    __shared__ int   redi[256];
    __shared__ int   redo[256];
    __shared__ float sred[256];
    __shared__ float t8v[8];
    __shared__ int   t8i[8];
    __shared__ int   iscal[1];
    const int b = blockIdx.x >> 2, q = blockIdx.x & 3;
    const int tid = threadIdx.x;
    const int v0 = q * NQ;
    const int v1 = (v0 + NQ < NV) ? (v0 + NQ) : NV;
    const float* lg = outl + b*NV;

    float lv[8]; int li[8];
    #pragma unroll
    for (int u = 0; u < 8; ++u) { lv[u] = -INFINITY; li[u] = 0x7fffffff; }
    for (int v = v0 + tid; v < v1; v += 256) {
        float x = lg[v];
        if (x > lv[7]) {
            int p = 7;
            while (p > 0 && x > lv[p-1]) { lv[p] = lv[p-1]; li[p] = li[p-1]; --p; }
            lv[p] = x; li[p] = v;
        }
    }
    #pragma unroll
    for (int u = 0; u < 8; ++u) { candv[tid*8 + u] = lv[u]; candi[tid*8 + u] = li[u]; }
    __syncthreads();
    int ptr = 0;
    for (int it = 0; it < 8; ++it) {
        redv[tid] = (ptr < 8) ? candv[tid*8 + ptr] : -INFINITY;
        redi[tid] = (ptr < 8) ? candi[tid*8 + ptr] : 0x7fffffff;
        redo[tid] = tid;
        __syncthreads();
        for (int off = 128; off > 0; off >>= 1) {
            if (tid < off) {
                float ov = redv[tid + off]; int oi = redi[tid + off];
                if (ov > redv[tid] || (ov == redv[tid] && oi < redi[tid])) {
                    redv[tid] = ov; redi[tid] = oi; redo[tid] = redo[tid + off];
                }
            }
            __syncthreads();
        }
        if (tid == 0) { t8v[it] = redv[0]; t8i[it] = redi[0]; iscal[0] = redo[0]; }
        __syncthreads();
        if (tid == iscal[0]) ++ptr;
        __syncthreads();
    }
    float Mp = t8v[0];
    float s1 = 0, s2 = 0;
    for (int v = v0 + tid; v < v1; v += 256) {
        float x = lg[v];
        float ee = expf(x - Mp);
        s1 += ee; s2 += x * ee;
    }
    redv[tid] = s1; sred[tid] = s2;
    __syncthreads();
    for (int off = 128; off > 0; off >>= 1) {
        if (tid < off) { redv[tid] += redv[tid+off]; sred[tid] += sred[tid+off]; }
        __syncthreads();
    }
    if (tid == 0) {
        int base = WS_P6 + (b*4 + q)*20;
        #pragma unroll
        for (int u = 0; u < 8; ++u) { ws[base + u] = t8v[u]; ((int*)ws)[base + 8 + u] = t8i[u]; }
        ws[base + 16] = Mp; ws[base + 17] = redv[0]; ws[base + 18] = sred[0];
    }
}

// =====================================================================
// K6b: per batch: merge partials, H, E_exp, rho, mu, m_next, A_next
// =====================================================================
__global__ __launch_bounds__(256) void k6b_final(
    const float* __restrict__ h_t, const float* __restrict__ A_t,
    const float* __restrict__ E, const float* __restrict__ e_mask,
    const float* __restrict__ G_t,
    const float* __restrict__ wmu_w, const float* __restrict__ wmu_b,
    const float* __restrict__ ws, float* __restrict__ out)
{
    __shared__ float mv[32];
    __shared__ int   mi[32];
    __shared__ float t8v[8];
    __shared__ int   t8i[8];
    __shared__ float toppsh[8];
    __shared__ float redv[256];
    __shared__ float uvec[64], eexp[64], msh[64], emsh[64];
    __shared__ float scal[4];
    const int b = blockIdx.x, tid = threadIdx.x;

    if (tid < 32) {
        int base = WS_P6 + (b*4 + (tid >> 3))*20;
        mv[tid] = ws[base + (tid & 7)];
        mi[tid] = ((const int*)ws)[base + 8 + (tid & 7)];
    }
    __syncthreads();
    if (tid == 0) {
        unsigned used = 0;
        for (int it = 0; it < 8; ++it) {
            float best = -INFINITY; int bi = 0x7fffffff, bs = 0;
            for (int c = 0; c < 32; ++c) {
                if (used & (1u << c)) continue;
                float x = mv[c];
                if (x > best || (x == best && mi[c] < bi)) { best = x; bi = mi[c]; bs = c; }
            }
            used |= 1u << bs; t8v[it] = best; t8i[it] = bi;
        }
        float M = t8v[0];
        float s1 = 0, s2 = 0;
        for (int q = 0; q < 4; ++q) {
            int base = WS_P6 + (b*4 + q)*20;
            float sc_ = expf(ws[base + 16] - M);
            s1 += ws[base + 17] * sc_; s2 += ws[base + 18] * sc_;
        }
        scal[0] = M + logf(s1) - s2 / s1;       // H
        float ts = 0, tv_[8];
        #pragma unroll
        for (int u = 0; u < 8; ++u) { tv_[u] = expf(t8v[u] - M); ts += tv_[u]; }
        #pragma unroll
        for (int u = 0; u < 8; ++u) toppsh[u] = tv_[u] / ts;
    }
    __syncthreads();
    if (tid < 64) {
        float u_ = 0;
        #pragma unroll
        for (int j = 0; j < 8; ++j) u_ += toppsh[j] * E[t8i[j]*64 + tid];
        uvec[tid] = u_;
    }
    __syncthreads();
    if (tid < 64) {
        const float* Qb = ws + WS_Q + b*4096;
        float a = 0;
        for (int p = 0; p < 64; ++p) a += uvec[p] * Qb[p*64 + tid];
        eexp[tid] = a;
    }
    __syncthreads();
    {   // rho
        const float* Gb = G_t + b*4096;
        const float* HL = ws + WS_HLIE + b*64;
        float a = 0;
        #pragma unroll 4
        for (int t2 = 0; t2 < 16; ++t2) {
            int idx = tid*16 + t2;
            int p = idx >> 6, q = idx & 63;
            a += (eexp[p] - HL[p]) * Gb[idx] * (eexp[q] - HL[q]);
        }
        redv[tid] = a;
    }
    __syncthreads();
    for (int off = 128; off > 0; off >>= 1) {
        if (tid < off) redv[tid] += redv[tid + off];
        __syncthreads();
    }
    if (tid == 0) scal[1] = redv[0];
    __syncthreads();
    // mu
    float pm = 0;
    for (int k = tid; k < 1024; k += 256) pm += h_t[b*1024 + k] * wmu_w[k];
    if (tid < 64) pm += ws[WS_CT + b*64 + tid] * wmu_w[1024 + tid];
    redv[tid] = pm;
    __syncthreads();
    for (int off = 128; off > 0; off >>= 1) {
        if (tid < off) redv[tid] += redv[tid + off];
        __syncthreads();
    }
    if (tid == 0) {
        float z = redv[0] + scal[0]*wmu_w[1088] + scal[1]*wmu_w[1089] + wmu_b[0];
        scal[2] = 1.0f / (1.0f + expf(-z));
    }
    __syncthreads();
    if (tid < 64) {
        float mu = scal[2];
        float em = e_mask[b*64 + tid];
        float m = mu*em + (1.0f - mu)*eexp[tid];
        out[OUT_M + b*64 + tid] = m;
        msh[tid] = m; emsh[tid] = em;
    }
    __syncthreads();
    for (int idx = tid; idx < 4096; idx += 256) {
        int i = idx >> 6, j = idx & 63;
        out[OUT_A + b*4096 + idx] = A_t[b*4096 + idx]
            + 0.1f*(msh[i]*emsh[j] - msh[j]*emsh[i]);
    }
}

// =====================================================================
extern "C" void kernel_launch(void* const* d_in, const int* in_sizes, int n_in,
                              void* d_out, int out_size, void* d_ws, size_t ws_size,
                              hipStream_t stream)
{
    const float* h_t      = (const float*)d_in[0];
    const float* A_t      = (const float*)d_in[1];
    const float* B_t      = (const float*)d_in[2];
    const float* E        = (const float*)d_in[3];
    const float* e_mask   = (const float*)d_in[4];
    const float* G_t      = (const float*)d_in[5];
    const float* WQ_w     = (const float*)d_in[7];
    const float* WQ_b     = (const float*)d_in[8];
    const float* WK_w     = (const float*)d_in[9];
    const float* WK_b     = (const float*)d_in[10];
    const float* WV_w     = (const float*)d_in[11];
    const float* WV_b     = (const float*)d_in[12];
    const float* WC_w     = (const float*)d_in[13];
    const float* WC_b     = (const float*)d_in[14];
    const float* WO_w     = (const float*)d_in[15];
    const float* WG_w     = (const float*)d_in[16];
    const float* WG_b     = (const float*)d_in[17];
    const float* wgamma_w = (const float*)d_in[18];
    const float* wgamma_b = (const float*)d_in[19];
    const float* wmu_w    = (const float*)d_in[20];
    const float* wmu_b    = (const float*)d_in[21];
    const float* gdown_w  = (const float*)d_in[22];
    const float* Sigma_inv= (const float*)d_in[23];
    const float* hlie_w   = (const float*)d_in[24];
    const float* hlie_b   = (const float*)d_in[25];
    float* out = (float*)d_out;
    float* ws  = (float*)d_ws;

    k1_prep<<<9, 256, 0, stream>>>(h_t, A_t, WG_w, WG_b, Sigma_inv, ws);
    k2_batch<<<8, 256, 0, stream>>>(h_t, G_t, WQ_w, WQ_b, WK_w, WK_b,
                                    wgamma_w, hlie_w, hlie_b, ws);
    k3_scores<<<32, 256, 0, stream>>>(B_t, ws);
    k4_mid<<<8, 256, 0, stream>>>(A_t, B_t, WV_w, WV_b, WC_w, WC_b, WG_w, WG_b,
                                  wgamma_w, wgamma_b, gdown_w, Sigma_inv, ws);
    k5_logits<<<393, 128, 0, stream>>>(E, WO_w, ws, out);
    k6a_scan<<<32, 256, 0, stream>>>(out, ws);
    k6b_final<<<8, 256, 0, stream>>>(h_t, A_t, E, e_mask, G_t, wmu_w, wmu_b, ws, out);
}

// Round 3
// 594.938 us; speedup vs baseline: 1.8108x; 1.2565x over previous
//
#include <hip/hip_runtime.h>
#include <math.h>

// ---------------- problem constants ----------------
#define NV    50257
#define OUT_M 402056            // 8*50257
#define OUT_A 402568            // + 8*64
#define SCALE 0.125f            // 1/sqrt(64)

// ---------------- ws layout (float offsets) ----------------
#define WS_Q      0             // [8][64][64]
#define WS_HTR    32768         // [1024][8]
#define WS_S      40960         // [64][64]  S = WG Sigma WG^T
#define WS_TV     45056         // [64]
#define WS_C0     45120         // [1] (pad 8)
#define WS_IU     45128         // [2016] int: packed i*64+j upper-tri pairs
#define WS_HLIE   47144         // [8][64]
#define WS_W1     47656         // [8][64]
#define WS_S0     48168         // [8]
#define WS_GH     48176         // [8]
#define WS_WMAT   48192         // [8][64][64]  W = Q G Q^T
#define WS_SC     80960         // [8][256] scores
#define WS_WB     83008         // [8][64]
#define WS_CONSTB 83520         // [8]
#define WS_GAMMA  83528         // [8]
#define WS_CT     83536         // [8][64]
#define WS_P6     84048         // [8][4][20] top-k partials

// =====================================================================
// K1: blocks 0..7 -> register-resident Gauss-Jordan (I-A)Q=(I+A) + htr
//     block 8     -> S, tvec, c0, iu pair table
// Thread (i = tid&63 row, cb = tid>>6 col-block of 32) holds 32 floats
// of the augmented [I-A | I+A] in registers. Per iteration: pivot row
// via float4 LDS writes + f-column via LDS, double-buffered, 1 barrier.
// =====================================================================
__global__ __launch_bounds__(256) void k1_prep(
    const float* __restrict__ h_t, const float* __restrict__ A_t,
    const float* __restrict__ WG_w, const float* __restrict__ WG_b,
    const float* __restrict__ Sigma_inv, float* __restrict__ ws)
{
    const int tid = threadIdx.x;
    const int blk = blockIdx.x;
    if (blk < 8) {
        const int b = blk;
        __shared__ float Ash[64][65];
        __shared__ float piv[2][132];
        __shared__ float fr[2][64];
        __shared__ float dsh[64];
        const int i  = tid & 63;
        const int cb = __builtin_amdgcn_readfirstlane(tid >> 6);

        for (int idx = tid; idx < 4096; idx += 256)
            Ash[idx >> 6][idx & 63] = A_t[b*4096 + idx];
        __syncthreads();

        float w[32];
        if (cb < 2) {
            #pragma unroll
            for (int jj = 0; jj < 32; ++jj) {
                int j = cb*32 + jj;
                w[jj] = (i == j ? 1.0f : 0.0f) - Ash[i][j];
            }
        } else {
            #pragma unroll
            for (int jj = 0; jj < 32; ++jj) {
                int j = (cb - 2)*32 + jj;
                w[jj] = (i == j ? 1.0f : 0.0f) + Ash[i][j];
            }
        }
        __syncthreads();

        #pragma unroll
        for (int k = 0; k < 64; ++k) {
            const int kb  = k >> 5;
            const int sel = k & 1;
            if (cb == kb) fr[sel][i] = w[k & 31];
            if (i == k) {
                #pragma unroll
                for (int q4 = 0; q4 < 8; ++q4)
                    *(float4*)&piv[sel][cb*32 + q4*4] =
                        make_float4(w[q4*4], w[q4*4+1], w[q4*4+2], w[q4*4+3]);
            }
            __syncthreads();
            float pk = piv[sel][k];
            float f = (i == k) ? 0.0f : (fr[sel][i] / pk);
            #pragma unroll
            for (int jj = 0; jj < 32; ++jj)
                w[jj] -= f * piv[sel][cb*32 + jj];
        }

        if (cb == (i >> 5)) dsh[i] = w[i & 31];
        __syncthreads();
        if (cb >= 2) {
            float dinv = 1.0f / dsh[i];
            #pragma unroll
            for (int jj = 0; jj < 32; ++jj)
                Ash[i][(cb - 2)*32 + jj] = w[jj] * dinv;
        }
        __syncthreads();
        for (int idx = tid; idx < 4096; idx += 256)
            ws[WS_Q + b*4096 + idx] = Ash[idx >> 6][idx & 63];
        for (int k = tid; k < 1024; k += 256)
            ws[WS_HTR + k*8 + b] = h_t[b*1024 + k];
    } else {
        // ---- block 8: S = WG Sigma WG^T, tvec, c0, iu table ----
        __shared__ float Wsc[64][65];
        __shared__ float Wr[64][65];
        __shared__ float sig[64], bg[64];
        const int a  = tid & 63;
        const int cb = __builtin_amdgcn_readfirstlane(tid >> 6);
        if (tid < 64) { sig[tid] = Sigma_inv[tid]; bg[tid] = WG_b[tid]; }
        __syncthreads();
        for (int idx = tid; idx < 4096; idx += 256) {
            int r = idx >> 6, c = idx & 63;
            float wv = WG_w[idx];
            Wr[r][c] = wv; Wsc[r][c] = wv * sig[c];
        }
        __syncthreads();
        float t[16];
        #pragma unroll
        for (int j = 0; j < 16; ++j) t[j] = 0.0f;
        for (int p = 0; p < 64; ++p) {
            float wv = Wsc[a][p];
            #pragma unroll
            for (int jj = 0; jj < 16; ++jj) t[jj] += wv * Wr[cb*16 + jj][p];
        }
        #pragma unroll
        for (int jj = 0; jj < 16; ++jj)
            ws[WS_S + a*64 + cb*16 + jj] = t[jj];
        if (cb == 0) {
            float s = 0.0f;
            for (int p = 0; p < 64; ++p) s += Wsc[a][p] * bg[p];
            ws[WS_TV + a] = 2.0f * s;
        }
        if (tid == 0) {
            float c0 = 0.0f;
            for (int p = 0; p < 64; ++p) c0 += sig[p] * bg[p] * bg[p];
            ws[WS_C0] = c0;
        }
        for (int s = tid; s < 2016; s += 256) {
            int i2 = 0, f = 0;
            while (f + (63 - i2) <= s) { f += 63 - i2; ++i2; }
            int j = i2 + 1 + (s - f);
            ((int*)ws)[WS_IU + s] = i2*64 + j;
        }
    }
}

// =====================================================================
// K2: one block per batch. q_t/h_lie GEMVs, qkvec, Ghl, w1, s0, gh,
//     W = Q G Q^T. All matrices staged in LDS; h staged in LDS.
// =====================================================================
__global__ __launch_bounds__(256) void k2_batch(
    const float* __restrict__ h_t, const float* __restrict__ G_t,
    const float* __restrict__ WQ_w, const float* __restrict__ WQ_b,
    const float* __restrict__ WK_w, const float* __restrict__ WK_b,
    const float* __restrict__ wgamma_w,
    const float* __restrict__ hlie_w, const float* __restrict__ hlie_b,
    float* __restrict__ ws)
{
    __shared__ float Qsh[64][65], Gsh[64][65];
    __shared__ float hsh[1024];
    __shared__ float part[4][64], partb[4][64];
    __shared__ float qt[64], hl[64], qkv[64], ghl[64], v0[64], red64[64];
    __shared__ float scal[4];

    const int b = blockIdx.x, tid = threadIdx.x;
    const int lane = tid & 63;
    const int gu = __builtin_amdgcn_readfirstlane(tid >> 6);
    const int col0 = gu * 16;
    const float* Qb = ws + WS_Q + b*4096;
    const float* Gb = G_t + b*4096;

    for (int idx = tid; idx < 4096; idx += 256) {
        int r = idx >> 6, c = idx & 63;
        Qsh[r][c] = Qb[idx];
        Gsh[r][c] = Gb[idx];
    }
    for (int idx = tid; idx < 1024; idx += 256) hsh[idx] = h_t[b*1024 + idx];
    __syncthreads();
    // GEMVs from h (h broadcast from LDS)
    {
        float aq = 0, ah = 0, ag = 0;
        #pragma unroll 8
        for (int kk = 0; kk < 256; ++kk) {
            int k = gu*256 + kk;
            float hv = hsh[k];
            aq += hv * WQ_w[k*64 + lane];
            ah += hv * hlie_w[k*64 + lane];
            ag += hv * wgamma_w[k];
        }
        part[gu][lane] = aq; partb[gu][lane] = ah;
        if (lane == 0) red64[gu] = ag;
    }
    __syncthreads();
    if (tid < 64) {
        qt[tid] = part[0][tid]+part[1][tid]+part[2][tid]+part[3][tid] + WQ_b[tid];
        hl[tid] = partb[0][tid]+partb[1][tid]+partb[2][tid]+partb[3][tid] + hlie_b[tid];
    }
    if (tid == 0) scal[0] = red64[0]+red64[1]+red64[2]+red64[3];   // gamma_h
    __syncthreads();
    // qkvec = WK q_t ; qkb = q_t . WK_b
    {
        float acc = 0;
        #pragma unroll
        for (int jj = 0; jj < 16; ++jj) acc += WK_w[lane*64 + col0 + jj] * qt[col0 + jj];
        part[gu][lane] = acc;
    }
    if (tid < 64) red64[tid] = qt[tid] * WK_b[tid];
    __syncthreads();
    if (tid < 64) qkv[tid] = part[0][tid]+part[1][tid]+part[2][tid]+part[3][tid];
    if (tid == 0) { float s = 0; for (int j = 0; j < 64; ++j) s += red64[j]; scal[1] = s; }
    __syncthreads();
    // ghl = G hl ; hGh
    {
        float acc = 0;
        #pragma unroll
        for (int jj = 0; jj < 16; ++jj) acc += Gsh[lane][col0 + jj] * hl[col0 + jj];
        part[gu][lane] = acc;
    }
    __syncthreads();
    if (tid < 64) {
        float g = part[0][tid]+part[1][tid]+part[2][tid]+part[3][tid];
        ghl[tid] = g; red64[tid] = hl[tid]*g;
    }
    __syncthreads();
    if (tid == 0) { float s = 0; for (int j = 0; j < 64; ++j) s += red64[j]; scal[2] = s; }
    if (tid < 64) v0[tid] = SCALE*qkv[tid] + ghl[tid];
    __syncthreads();
    // w1 = Q v0
    {
        float acc = 0;
        #pragma unroll
        for (int jj = 0; jj < 16; ++jj) acc += Qsh[lane][col0+jj] * v0[col0+jj];
        part[gu][lane] = acc;
    }
    __syncthreads();
    if (tid < 64) {
        ws[WS_W1 + b*64 + tid] = part[0][tid]+part[1][tid]+part[2][tid]+part[3][tid];
        ws[WS_HLIE + b*64 + tid] = hl[tid];
    }
    if (tid == 0) {
        ws[WS_S0 + b] = SCALE*scal[1] - 0.5f*scal[2];
        ws[WS_GH + b] = scal[0];
    }
    // T = Q G into regs
    float t[16];
    #pragma unroll
    for (int j = 0; j < 16; ++j) t[j] = 0;
    for (int r = 0; r < 64; ++r) {
        float qv = Qsh[lane][r];
        #pragma unroll
        for (int j = 0; j < 16; ++j) t[j] += qv * Gsh[r][col0+j];
    }
    __syncthreads();
    #pragma unroll
    for (int j = 0; j < 16; ++j) Gsh[lane][col0+j] = t[j];   // Gsh now holds T
    __syncthreads();
    // W = T Q^T ; Q^T[q][c] = Qsh[c][q] (uniform -> broadcast)
    float w[16];
    #pragma unroll
    for (int j = 0; j < 16; ++j) w[j] = 0;
    for (int q = 0; q < 64; ++q) {
        float tv = Gsh[lane][q];
        #pragma unroll
        for (int j = 0; j < 16; ++j) w[j] += tv * Qsh[col0+j][q];
    }
    #pragma unroll
    for (int j = 0; j < 16; ++j)
        ws[WS_WMAT + b*4096 + (col0+j)*64 + lane] = w[j];
}

// =====================================================================
// K3: 32 blocks = (b, quarter). scores via b W b^T from LDS.
// =====================================================================
__global__ __launch_bounds__(256) void k3_scores(
    const float* __restrict__ B_t, float* __restrict__ ws)
{
    __shared__ float Bsh[64][65];
    __shared__ float Wsh[64][64];
    __shared__ float w1sh[64];
    __shared__ float part[4][64];
    const int b = blockIdx.x >> 2, q4 = blockIdx.x & 3;
    const int tid = threadIdx.x, lane = tid & 63;
    const int gu = __builtin_amdgcn_readfirstlane(tid >> 6);
    const int col0 = gu * 16;
    for (int idx = tid; idx < 4096; idx += 256) {
        int r = idx >> 6, c = idx & 63;
        Bsh[r][c] = B_t[b*16384 + (q4*64 + r)*64 + c];
        Wsh[r][c] = ws[WS_WMAT + b*4096 + idx];
    }
    if (tid < 64) w1sh[tid] = ws[WS_W1 + b*64 + tid];
    __syncthreads();
    float t[16];
    #pragma unroll
    for (int j = 0; j < 16; ++j) t[j] = 0;
    for (int p = 0; p < 64; ++p) {
        float bv = Bsh[lane][p];
        #pragma unroll
        for (int j = 0; j < 16; ++j) t[j] += bv * Wsh[p][col0+j];
    }
    float ps = 0;
    #pragma unroll
    for (int j = 0; j < 16; ++j) ps += (w1sh[col0+j] - 0.5f*t[j]) * Bsh[lane][col0+j];
    part[gu][lane] = ps;
    __syncthreads();
    if (tid < 64)
        ws[WS_SC + b*256 + q4*64 + tid] =
            part[0][tid]+part[1][tid]+part[2][tid]+part[3][tid] + ws[WS_S0 + b];
}

// =====================================================================
// K4: per batch: softmax(alpha), c chain, g_proj (table), gamma, w_b.
// =====================================================================
__global__ __launch_bounds__(256) void k4_mid(
    const float* __restrict__ A_t, const float* __restrict__ B_t,
    const float* __restrict__ WV_w, const float* __restrict__ WV_b,
    const float* __restrict__ WC_w, const float* __restrict__ WC_b,
    const float* __restrict__ WG_w, const float* __restrict__ WG_b,
    const float* __restrict__ wgamma_w, const float* __restrict__ wgamma_b,
    const float* __restrict__ gdown_w, const float* __restrict__ Sigma_inv,
    float* __restrict__ ws)
{
    __shared__ float alpha[256], rr[256];
    __shared__ float part[4][64];
    __shared__ float cBr[64], cB[64], ct[64], cw[64], crot[64], gp[64], uv[64];
    const int b = blockIdx.x, tid = threadIdx.x, lane = tid & 63;
    const int gu = __builtin_amdgcn_readfirstlane(tid >> 6);
    const int col0 = gu * 16;
    const float* Qb = ws + WS_Q + b*4096;

    float sv = ws[WS_SC + b*256 + tid];
    rr[tid] = sv; __syncthreads();
    for (int off = 128; off > 0; off >>= 1) { if (tid < off) rr[tid] = fmaxf(rr[tid], rr[tid+off]); __syncthreads(); }
    float smax = rr[0]; __syncthreads();
    float e = expf(sv - smax);
    rr[tid] = e; __syncthreads();
    for (int off = 128; off > 0; off >>= 1) { if (tid < off) rr[tid] += rr[tid+off]; __syncthreads(); }
    float den = rr[0]; __syncthreads();
    alpha[tid] = e / den;
    __syncthreads();
    // cB_raw = alpha @ B
    {
        float acc = 0;
        for (int nn = 0; nn < 64; ++nn) {
            int n = gu*64 + nn;
            acc += alpha[n] * B_t[b*16384 + n*64 + lane];
        }
        part[gu][lane] = acc;
    }
    __syncthreads();
    if (tid < 64) cBr[tid] = part[0][tid]+part[1][tid]+part[2][tid]+part[3][tid];
    __syncthreads();
    // cB = cBr @ Q
    {
        float acc = 0;
        #pragma unroll
        for (int pp = 0; pp < 16; ++pp) { int p = col0+pp; acc += cBr[p]*Qb[p*64+lane]; }
        part[gu][lane] = acc;
    }
    __syncthreads();
    if (tid < 64) cB[tid] = part[0][tid]+part[1][tid]+part[2][tid]+part[3][tid];
    __syncthreads();
    // c_t = cB @ WV + bv
    {
        float acc = 0;
        #pragma unroll
        for (int pp = 0; pp < 16; ++pp) { int p = col0+pp; acc += cB[p]*WV_w[p*64+lane]; }
        part[gu][lane] = acc;
    }
    __syncthreads();
    if (tid < 64) {
        float v = part[0][tid]+part[1][tid]+part[2][tid]+part[3][tid] + WV_b[tid];
        ct[tid] = v; ws[WS_CT + b*64 + tid] = v;
    }
    __syncthreads();
    // cw = c_t @ WC + cb
    {
        float acc = 0;
        #pragma unroll
        for (int pp = 0; pp < 16; ++pp) { int p = col0+pp; acc += ct[p]*WC_w[p*64+lane]; }
        part[gu][lane] = acc;
    }
    __syncthreads();
    if (tid < 64) cw[tid] = part[0][tid]+part[1][tid]+part[2][tid]+part[3][tid] + WC_b[tid];
    __syncthreads();
    // crot = cw @ Q
    {
        float acc = 0;
        #pragma unroll
        for (int pp = 0; pp < 16; ++pp) { int p = col0+pp; acc += cw[p]*Qb[p*64+lane]; }
        part[gu][lane] = acc;
    }
    __syncthreads();
    if (tid < 64) crot[tid] = part[0][tid]+part[1][tid]+part[2][tid]+part[3][tid];
    __syncthreads();
    // g_proj = g_t @ gdown (pair table), gamma parts
    {
        const int* iu = (const int*)ws + WS_IU;
        float accp = 0, accg = 0;
        #pragma unroll 4
        for (int ss = 0; ss < 504; ++ss) {
            int s = gu*504 + ss;
            int ij = iu[s];
            float av = A_t[b*4096 + ij];
            accp += av * gdown_w[s*64 + lane];
            accg += av * wgamma_w[1088 + s];
        }
        part[gu][lane] = accp;
        if (lane == 0) rr[gu] = accg;
    }
    if (tid < 64) rr[64 + tid] = ct[tid] * wgamma_w[1024 + tid];
    __syncthreads();
    if (tid < 64) {
        float g = part[0][tid]+part[1][tid]+part[2][tid]+part[3][tid];
        gp[tid] = g; uv[tid] = 2.0f * Sigma_inv[tid] * g;
    }
    if (tid == 0) {
        float gc = 0; for (int j = 0; j < 64; ++j) gc += rr[64 + j];
        float z = ws[WS_GH + b] + gc + rr[0]+rr[1]+rr[2]+rr[3] + wgamma_b[0];
        ws[WS_GAMMA + b] = 1.0f / (1.0f + expf(-z));
    }
    __syncthreads();
    // w_b = scale*crot + WG u ; const_b = bg.u - sum gp^2 sig
    {
        float acc = 0;
        #pragma unroll
        for (int pp = 0; pp < 16; ++pp) { int p = col0+pp; acc += WG_w[lane*64+p]*uv[p]; }
        part[gu][lane] = acc;
    }
    if (tid < 64) rr[tid] = WG_b[tid]*uv[tid] - gp[tid]*gp[tid]*Sigma_inv[tid];
    __syncthreads();
    if (tid < 64)
        ws[WS_WB + b*64 + tid] = SCALE*crot[tid]
            + part[0][tid]+part[1][tid]+part[2][tid]+part[3][tid];
    if (tid == 0) { float s = 0; for (int j = 0; j < 64; ++j) s += rr[j]; ws[WS_CONSTB + b] = s; }
}

// =====================================================================
// K5: fused logits. Phase1: sv quadratic (E,S staged in LDS).
//     Phase2: gd + WO stream with h broadcast from LDS.
// =====================================================================
#define KU 16
__global__ __launch_bounds__(128) void k5_logits(
    const float* __restrict__ E, const float* __restrict__ WO_w,
    const float* __restrict__ ws, float* __restrict__ out)
{
    __shared__ float smem[12608];   // 50.4 KB, two-phase reuse
    const int tid = threadIdx.x;
    const int vb = blockIdx.x * 128;
    const int v = vb + tid;
    const bool vok = v < NV;
    const int vv = vok ? v : NV - 1;

    // phase 1 partition
    float* Esh  = smem;            // [128][66]
    float* Ssh  = smem + 8448;     // [64][64]
    float* tvsh = smem + 12544;    // [64]
    for (int idx = tid; idx < 8192; idx += 128) {
        int r = idx >> 6, c = idx & 63;
        int vr = vb + r; if (vr >= NV) vr = NV - 1;
        Esh[r*66 + c] = E[vr*64 + c];
    }
    for (int idx = tid; idx < 4096; idx += 128) Ssh[idx] = ws[WS_S + idx];
    if (tid < 64) tvsh[tid] = ws[WS_TV + tid];
    __syncthreads();
    float sv = ws[WS_C0];
    {
        const float* er = Esh + tid*66;
        for (int jb = 0; jb < 4; ++jb) {
            float t[16];
            #pragma unroll
            for (int j = 0; j < 16; ++j) t[j] = 0;
            for (int p = 0; p < 64; ++p) {
                float ep = er[p];
                #pragma unroll
                for (int j = 0; j < 16; ++j) t[j] += ep * Ssh[p*64 + jb*16 + j];
            }
            #pragma unroll
            for (int j = 0; j < 16; ++j) sv += (t[j] + tvsh[jb*16+j]) * er[jb*16+j];
        }
    }
    __syncthreads();
    // phase 2 partition
    float* hsh  = smem;            // [1024][8]
    float* wbsh = smem + 8192;     // [8][64]
    float* gmsh = smem + 8704;     // [8]
    float* cbsh = smem + 8712;     // [8]
    for (int idx = tid; idx < 8192; idx += 128) hsh[idx] = ws[WS_HTR + idx];
    for (int idx = tid; idx < 512; idx += 128) wbsh[idx] = ws[WS_WB + idx];
    if (tid < 8) { gmsh[tid] = ws[WS_GAMMA + tid]; cbsh[tid] = ws[WS_CONSTB + tid]; }
    __syncthreads();
    // gd[b] = e . w_b
    float gd[8];
    #pragma unroll
    for (int bb = 0; bb < 8; ++bb) gd[bb] = 0;
    {
        const float4* E4 = (const float4*)(E + (size_t)vv * 64);
        #pragma unroll 4
        for (int p4 = 0; p4 < 16; ++p4) {
            float4 e4 = E4[p4];
            #pragma unroll
            for (int bb = 0; bb < 8; ++bb) {
                const float* wp = wbsh + bb*64 + p4*4;
                gd[bb] += e4.x*wp[0] + e4.y*wp[1] + e4.z*wp[2] + e4.w*wp[3];
            }
        }
    }
    // base logits: stream WO column, h from LDS broadcast
    float acc[8];
    #pragma unroll
    for (int bb = 0; bb < 8; ++bb) acc[bb] = 0;
    {
        const float* wo = WO_w + vv;
        for (int k0 = 0; k0 < 1024; k0 += KU) {
            float wr[KU];
            #pragma unroll
            for (int u = 0; u < KU; ++u) wr[u] = wo[(size_t)(k0 + u) * NV];
            #pragma unroll
            for (int u = 0; u < KU; ++u) {
                const float* hp = hsh + (k0 + u)*8;
                #pragma unroll
                for (int bb = 0; bb < 8; ++bb) acc[bb] = fmaf(hp[bb], wr[u], acc[bb]);
            }
        }
    }
    if (vok) {
        #pragma unroll
        for (int bb = 0; bb < 8; ++bb) {
            float gl = gd[bb] + cbsh[bb] - sv;
            out[bb*NV + v] = fmaf(gmsh[bb], gl, acc[bb]);
        }
    }
}

// =====================================================================
// K6a: 32 blocks = (b, quarter): partial top-8 + rescalable softmax sums
// =====================================================================
#define NQ 12565
__global__ __launch_bounds__(256) void k6a_scan(
    const float* __restrict__ outl, float* __restrict__ ws)
{
    __shared__ float candv[2048];
    __shared__ int   candi[2048];
    __shared__ float redv[256];
    __shared__ int   redi[256];
    __shared__ int   redo[256];
    __shared__ float sred[256];
    __shared__ float t8v[8];
    __shared__ int   t8i[8];
    __shared__ int   iscal[1];
    const int b = blockIdx.x >> 2, q = blockIdx.x & 3;
    const int tid = threadIdx.x;
    const int v0 = q * NQ;
    const int v1 = (v0 + NQ < NV) ? (v0 + NQ) : NV;
    const float* lg = outl + b*NV;

    float lv[8]; int li[8];
    #pragma unroll
    for (int u = 0; u < 8; ++u) { lv[u] = -INFINITY; li[u] = 0x7fffffff; }
    for (int v = v0 + tid; v < v1; v += 256) {
        float x = lg[v];
        if (x > lv[7]) {
            int p = 7;
            while (p > 0 && x > lv[p-1]) { lv[p] = lv[p-1]; li[p] = li[p-1]; --p; }
            lv[p] = x; li[p] = v;
        }
    }
    #pragma unroll
    for (int u = 0; u < 8; ++u) { candv[tid*8 + u] = lv[u]; candi[tid*8 + u] = li[u]; }
    __syncthreads();
    int ptr = 0;
    for (int it = 0; it < 8; ++it) {
        redv[tid] = (ptr < 8) ? candv[tid*8 + ptr] : -INFINITY;
        redi[tid] = (ptr < 8) ? candi[tid*8 + ptr] : 0x7fffffff;
        redo[tid] = tid;
        __syncthreads();
        for (int off = 128; off > 0; off >>= 1) {
            if (tid < off) {
                float ov = redv[tid + off]; int oi = redi[tid + off];
                if (ov > redv[tid] || (ov == redv[tid] && oi < redi[tid])) {
                    redv[tid] = ov; redi[tid] = oi; redo[tid] = redo[tid + off];
                }
            }
            __syncthreads();
        }
        if (tid == 0) { t8v[it] = redv[0]; t8i[it] = redi[0]; iscal[0] = redo[0]; }
        __syncthreads();
        if (tid == iscal[0]) ++ptr;
        __syncthreads();
    }
    float Mp = t8v[0];
    float s1 = 0, s2 = 0;
    for (int v = v0 + tid; v < v1; v += 256) {
        float x = lg[v];
        float ee = expf(x - Mp);
        s1 += ee; s2 += x * ee;
    }
    redv[tid] = s1; sred[tid] = s2;
    __syncthreads();
    for (int off = 128; off > 0; off >>= 1) {
        if (tid < off) { redv[tid] += redv[tid+off]; sred[tid] += sred[tid+off]; }
        __syncthreads();
    }
    if (tid == 0) {
        int base = WS_P6 + (b*4 + q)*20;
        #pragma unroll
        for (int u = 0; u < 8; ++u) { ws[base + u] = t8v[u]; ((int*)ws)[base + 8 + u] = t8i[u]; }
        ws[base + 16] = Mp; ws[base + 17] = redv[0]; ws[base + 18] = sred[0];
    }
}

// =====================================================================
// K6b: per batch: merge partials, H, E_exp, rho, mu, m_next, A_next
// =====================================================================
__global__ __launch_bounds__(256) void k6b_final(
    const float* __restrict__ h_t, const float* __restrict__ A_t,
    const float* __restrict__ E, const float* __restrict__ e_mask,
    const float* __restrict__ G_t,
    const float* __restrict__ wmu_w, const float* __restrict__ wmu_b,
    const float* __restrict__ ws, float* __restrict__ out)
{
    __shared__ float mv[32];
    __shared__ int   mi[32];
    __shared__ float t8v[8];
    __shared__ int   t8i[8];
    __shared__ float toppsh[8];
    __shared__ float redv[256];
    __shared__ float uvec[64], eexp[64], msh[64], emsh[64];
    __shared__ float scal[4];
    const int b = blockIdx.x, tid = threadIdx.x;

    if (tid < 32) {
        int base = WS_P6 + (b*4 + (tid >> 3))*20;
        mv[tid] = ws[base + (tid & 7)];
        mi[tid] = ((const int*)ws)[base + 8 + (tid & 7)];
    }
    __syncthreads();
    if (tid == 0) {
        unsigned used = 0;
        for (int it = 0; it < 8; ++it) {
            float best = -INFINITY; int bi = 0x7fffffff, bs = 0;
            for (int c = 0; c < 32; ++c) {
                if (used & (1u << c)) continue;
                float x = mv[c];
                if (x > best || (x == best && mi[c] < bi)) { best = x; bi = mi[c]; bs = c; }
            }
            used |= 1u << bs; t8v[it] = best; t8i[it] = bi;
        }
        float M = t8v[0];
        float s1 = 0, s2 = 0;
        for (int q = 0; q < 4; ++q) {
            int base = WS_P6 + (b*4 + q)*20;
            float sc_ = expf(ws[base + 16] - M);
            s1 += ws[base + 17] * sc_; s2 += ws[base + 18] * sc_;
        }
        scal[0] = M + logf(s1) - s2 / s1;       // H
        float ts = 0, tv_[8];
        #pragma unroll
        for (int u = 0; u < 8; ++u) { tv_[u] = expf(t8v[u] - M); ts += tv_[u]; }
        #pragma unroll
        for (int u = 0; u < 8; ++u) toppsh[u] = tv_[u] / ts;
    }
    __syncthreads();
    if (tid < 64) {
        float u_ = 0;
        #pragma unroll
        for (int j = 0; j < 8; ++j) u_ += toppsh[j] * E[t8i[j]*64 + tid];
        uvec[tid] = u_;
    }
    __syncthreads();
    if (tid < 64) {
        const float* Qb = ws + WS_Q + b*4096;
        float a = 0;
        for (int p = 0; p < 64; ++p) a += uvec[p] * Qb[p*64 + tid];
        eexp[tid] = a;
    }
    __syncthreads();
    {   // rho
        const float* Gb = G_t + b*4096;
        const float* HL = ws + WS_HLIE + b*64;
        float a = 0;
        #pragma unroll 4
        for (int t2 = 0; t2 < 16; ++t2) {
            int idx = tid*16 + t2;
            int p = idx >> 6, q = idx & 63;
            a += (eexp[p] - HL[p]) * Gb[idx] * (eexp[q] - HL[q]);
        }
        redv[tid] = a;
    }
    __syncthreads();
    for (int off = 128; off > 0; off >>= 1) {
        if (tid < off) redv[tid] += redv[tid + off];
        __syncthreads();
    }
    if (tid == 0) scal[1] = redv[0];
    __syncthreads();
    // mu
    float pm = 0;
    for (int k = tid; k < 1024; k += 256) pm += h_t[b*1024 + k] * wmu_w[k];
    if (tid < 64) pm += ws[WS_CT + b*64 + tid] * wmu_w[1024 + tid];
    redv[tid] = pm;
    __syncthreads();
    for (int off = 128; off > 0; off >>= 1) {
        if (tid < off) redv[tid] += redv[tid + off];
        __syncthreads();
    }
    if (tid == 0) {
        float z = redv[0] + scal[0]*wmu_w[1088] + scal[1]*wmu_w[1089] + wmu_b[0];
        scal[2] = 1.0f / (1.0f + expf(-z));
    }
    __syncthreads();
    if (tid < 64) {
        float mu = scal[2];
        float em = e_mask[b*64 + tid];
        float m = mu*em + (1.0f - mu)*eexp[tid];
        out[OUT_M + b*64 + tid] = m;
        msh[tid] = m; emsh[tid] = em;
    }
    __syncthreads();
    for (int idx = tid; idx < 4096; idx += 256) {
        int i = idx >> 6, j = idx & 63;
        out[OUT_A + b*4096 + idx] = A_t[b*4096 + idx]
            + 0.1f*(msh[i]*emsh[j] - msh[j]*emsh[i]);
    }
}

// =====================================================================
extern "C" void kernel_launch(void* const* d_in, const int* in_sizes, int n_in,
                              void* d_out, int out_size, void* d_ws, size_t ws_size,
                              hipStream_t stream)
{
    const float* h_t      = (const float*)d_in[0];
    const float* A_t      = (const float*)d_in[1];
    const float* B_t      = (const float*)d_in[2];
    const float* E        = (const float*)d_in[3];
    const float* e_mask   = (const float*)d_in[4];
    const float* G_t      = (const float*)d_in[5];
    const float* WQ_w     = (const float*)d_in[7];
    const float* WQ_b     = (const float*)d_in[8];
    const float* WK_w     = (const float*)d_in[9];
    const float* WK_b     = (const float*)d_in[10];
    const float* WV_w     = (const float*)d_in[11];
    const float* WV_b     = (const float*)d_in[12];
    const float* WC_w     = (const float*)d_in[13];
    const float* WC_b     = (const float*)d_in[14];
    const float* WO_w     = (const float*)d_in[15];
    const float* WG_w     = (const float*)d_in[16];
    const float* WG_b     = (const float*)d_in[17];
    const float* wgamma_w = (const float*)d_in[18];
    const float* wgamma_b = (const float*)d_in[19];
    const float* wmu_w    = (const float*)d_in[20];
    const float* wmu_b    = (const float*)d_in[21];
    const float* gdown_w  = (const float*)d_in[22];
    const float* Sigma_inv= (const float*)d_in[23];
    const float* hlie_w   = (const float*)d_in[24];
    const float* hlie_b   = (const float*)d_in[25];
    float* out = (float*)d_out;
    float* ws  = (float*)d_ws;

    k1_prep<<<9, 256, 0, stream>>>(h_t, A_t, WG_w, WG_b, Sigma_inv, ws);
    k2_batch<<<8, 256, 0, stream>>>(h_t, G_t, WQ_w, WQ_b, WK_w, WK_b,
                                    wgamma_w, hlie_w, hlie_b, ws);
    k3_scores<<<32, 256, 0, stream>>>(B_t, ws);
    k4_mid<<<8, 256, 0, stream>>>(A_t, B_t, WV_w, WV_b, WC_w, WC_b, WG_w, WG_b,
                                  wgamma_w, wgamma_b, gdown_w, Sigma_inv, ws);
    k5_logits<<<393, 128, 0, stream>>>(E, WO_w, ws, out);
    k6a_scan<<<32, 256, 0, stream>>>(out, ws);
    k6b_final<<<8, 256, 0, stream>>>(h_t, A_t, E, e_mask, G_t, wmu_w, wmu_b, ws, out);
}